// Round 1
// baseline (13401.717 us; speedup 1.0000x reference)
//
#include <hip/hip_runtime.h>
#include <hip/hip_bf16.h>
#include <stdint.h>

#define T_LEN 4096
#define D_DIM 256
#define HDIM 256
#define G4 1024          // 4*HD gate rows per direction
#define NTAGS 32
#define START_TAG 30
#define STOP_TAG 31

typedef unsigned long long u64;
typedef unsigned int u32;

__device__ __forceinline__ float sigf(float x){ return 1.0f/(1.0f+expf(-x)); }

// ---------------------------------------------------------------------------
// K1: embedding gather + input projections xg = E[seq] @ Wih^T + (bih+bhh)
// grid: 4096 blocks = 512 t-tiles x 8 col-tiles of 256; block 256 threads.
// xg_b[t] corresponds to x[T-1-t] (backward scan order).
// ---------------------------------------------------------------------------
__global__ __launch_bounds__(256) void k_xg(const int* __restrict__ seq,
    const float* __restrict__ E,
    const float* __restrict__ Wf, const float* __restrict__ bihf, const float* __restrict__ bhhf,
    const float* __restrict__ Wb, const float* __restrict__ bihb, const float* __restrict__ bhhb,
    float* __restrict__ xg_f, float* __restrict__ xg_b)
{
    __shared__ __align__(16) float xsh[8][D_DIM];
    __shared__ int sq[8];
    const int b = blockIdx.x, tb = b >> 3, cb = b & 7, j = threadIdx.x;
    if (j < 8) sq[j] = seq[tb*8 + j];
    __syncthreads();
    #pragma unroll
    for (int r = 0; r < 8; ++r) xsh[r][j] = E[(size_t)sq[r]*D_DIM + j];
    __syncthreads();
    const int col = cb*256 + j;      // 0..2047
    const int d   = col >> 10;       // 0 fwd, 1 bwd
    const int row = col & 1023;
    const float* W = d ? Wb : Wf;
    const float bias = d ? (bihb[row] + bhhb[row]) : (bihf[row] + bhhf[row]);
    const float4* wr = reinterpret_cast<const float4*>(W + (size_t)row*D_DIM);
    float acc[8];
    #pragma unroll
    for (int r=0;r<8;++r) acc[r] = 0.f;
    for (int kk = 0; kk < D_DIM/4; ++kk){
        float4 wv = wr[kk];
        #pragma unroll
        for (int r=0;r<8;++r){
            float4 xv = reinterpret_cast<const float4*>(xsh[r])[kk];
            acc[r] = fmaf(wv.x, xv.x, fmaf(wv.y, xv.y, fmaf(wv.z, xv.z, fmaf(wv.w, xv.w, acc[r]))));
        }
    }
    #pragma unroll
    for (int r=0;r<8;++r){
        const int t = tb*8 + r;
        const float v = acc[r] + bias;
        if (d == 0) xg_f[(size_t)t*G4 + row] = v;
        else        xg_b[(size_t)(T_LEN-1-t)*G4 + row] = v;
    }
}

// ---------------------------------------------------------------------------
// K2: bidirectional LSTM recurrence. 8 persistent blocks:
//   block = (dir d = blk>>2, quarter q = blk&3). Each block owns 256 gate rows
//   (4 gates x 64 hidden units), weights fully register-resident (256 VGPRs).
// Cross-block h broadcast: packed (tag<<32 | h_bits) 8B agent-scope atomics,
// parity double-buffered; exact-tag polling needs no fences (data inside the
// atomic word). Replay-safe: tags 1..4096 fresh each launch; stale tags
// (4095/4096/0xAAAAAAAA) never match.
// ---------------------------------------------------------------------------
__global__ __launch_bounds__(256,1) void k_lstm(
    const float* __restrict__ Whh_f, const float* __restrict__ Whh_b,
    const float* __restrict__ xgf, const float* __restrict__ xgb,
    const float* __restrict__ h0, const float* __restrict__ c0,
    float* __restrict__ hs_f, float* __restrict__ hs_b,
    u64* __restrict__ hbuf_all)
{
    const int blk = blockIdx.x;
    const int d = blk >> 2, q = blk & 3;
    const int j = threadIdx.x;        // 0..255
    const int gi = j >> 6, uu = j & 63;
    const int row = gi*256 + q*64 + uu;          // gate row in [0,1024)
    const float* __restrict__ Whh = d ? Whh_b : Whh_f;
    const float* __restrict__ xg  = d ? xgb : xgf;
    float* __restrict__ hs = d ? hs_b : hs_f;
    u64* __restrict__ hb = hbuf_all + (size_t)d*2*HDIM;   // [parity][unit]

    __shared__ __align__(16) float h_sh[HDIM];
    __shared__ float g_sh[256];

    float4 wv[64];                    // 256 VGPRs of weights
    {
        const float4* wr = reinterpret_cast<const float4*>(Whh + (size_t)row*HDIM);
        #pragma unroll
        for (int kk=0; kk<64; ++kk) wv[kk] = wr[kk];
    }
    h_sh[j] = h0[d*HDIM + j];
    float c = (j < 64) ? c0[d*HDIM + q*64 + j] : 0.0f;
    float xgc = xg[row];              // xg[0][row]
    __syncthreads();

    const int ownlo = q*64, ownhi = q*64 + 64;
    for (int t = 0; t < T_LEN; ++t){
        float ax=0.f, ay=0.f, az=0.f, aw=0.f;
        const float4* h4 = reinterpret_cast<const float4*>(h_sh);
        #pragma unroll
        for (int kk=0;kk<64;++kk){
            float4 hv = h4[kk];
            ax = fmaf(wv[kk].x, hv.x, ax);
            ay = fmaf(wv[kk].y, hv.y, ay);
            az = fmaf(wv[kk].z, hv.z, az);
            aw = fmaf(wv[kk].w, hv.w, aw);
        }
        g_sh[j] = xgc + ((ax+ay)+(az+aw));
        {   // prefetch next step's xg
            const int tn = (t+1 < T_LEN) ? (t+1) : t;
            xgc = xg[(size_t)tn*G4 + row];
        }
        __syncthreads();              // B1: gates ready, h_sh reads done
        const int par = (t+1) & 1;
        if (j < 64){
            const int u = ownlo + j;
            const float ig = sigf(g_sh[j]);
            const float fg = sigf(g_sh[64+j]);
            const float gg = tanhf(g_sh[128+j]);
            const float og = sigf(g_sh[192+j]);
            c = fg*c + ig*gg;
            const float h = og*tanhf(c);
            const u64 pk = ((u64)(u32)(t+1) << 32) | (u64)__float_as_uint(h);
            __hip_atomic_store(&hb[par*HDIM + u], pk, __ATOMIC_RELAXED, __HIP_MEMORY_SCOPE_AGENT);
            h_sh[u] = h;
            hs[(size_t)(d==0 ? t : (T_LEN-1-t))*HDIM + u] = h;
        }
        if (t+1 < T_LEN){
            const int u = j;          // unit this thread is responsible for
            if (u < ownlo || u >= ownhi){
                u64 pk;
                do {
                    pk = __hip_atomic_load(&hb[par*HDIM + u], __ATOMIC_RELAXED, __HIP_MEMORY_SCOPE_AGENT);
                } while ((u32)(pk >> 32) != (u32)(t+1));
                h_sh[u] = __uint_as_float((u32)pk);
            }
        }
        __syncthreads();              // B2: h_sh = h_t complete
    }
}

// ---------------------------------------------------------------------------
// K3: feats[t][tag] = [hf[t]; hb[t]] . W_out[tag] + b_out[tag]  (f64 accum)
// ---------------------------------------------------------------------------
__global__ __launch_bounds__(256) void k_feats(
    const float* __restrict__ hs_f, const float* __restrict__ hs_b,
    const float* __restrict__ W_out, const float* __restrict__ b_out,
    float* __restrict__ feats)
{
    __shared__ __align__(16) float fsh[8][512];
    const int tb = blockIdx.x, j = threadIdx.x;
    #pragma unroll
    for (int r=0;r<8;++r){
        const int t = tb*8 + r;
        fsh[r][j]       = hs_f[(size_t)t*HDIM + j];
        fsh[r][256 + j] = hs_b[(size_t)t*HDIM + j];
    }
    __syncthreads();
    const int tsub = j >> 5, tag = j & 31;
    const float4* wr = reinterpret_cast<const float4*>(W_out + (size_t)tag*512);
    double acc = (double)b_out[tag];
    for (int kk=0; kk<128; ++kk){
        float4 wvv = wr[kk];
        float4 hv = reinterpret_cast<const float4*>(fsh[tsub])[kk];
        acc += (double)wvv.x*hv.x + (double)wvv.y*hv.y + (double)wvv.z*hv.z + (double)wvv.w*hv.w;
    }
    feats[(size_t)(tb*8+tsub)*NTAGS + tag] = (float)acc;
}

// ---------------------------------------------------------------------------
// K4: Viterbi in f64 (order-independent per-step rounding), first-index tie
// rule matching np.argmax. Wave 0 scans; waves 1-3 double-buffer feat chunks.
// Then LDS-chunked serial backtrace.
// ---------------------------------------------------------------------------
__global__ __launch_bounds__(256,1) void k_viterbi(
    const float* __restrict__ feats, const float* __restrict__ trans,
    unsigned char* __restrict__ bp_g, float* __restrict__ out)
{
    __shared__ __align__(16) float fbuf[2][256*NTAGS];   // 2 x 32KB
    __shared__ double fv_sh[NTAGS];
    __shared__ double term_sh[NTAGS];
    __shared__ int best_sh;
    const int j = threadIdx.x;
    const int n = j & 31, ph = (j >> 5) & 1;
    const bool scanlane = (j < 64);
    double tr[16];
    if (scanlane){
        #pragma unroll
        for (int i=0;i<16;++i) tr[i] = (double)trans[n*NTAGS + ph*16 + i];
    }
    double fv = (n == START_TAG) ? 0.0 : -10000.0;

    const int CH = 256, NCH = T_LEN / CH;  // 16 chunks
    for (int idx = j; idx < CH*NTAGS; idx += 256) fbuf[0][idx] = feats[idx];
    __syncthreads();
    for (int cc = 0; cc < NCH; ++cc){
        const int buf = cc & 1;
        if (scanlane){
            for (int s = 0; s < CH; ++s){
                const int t = cc*CH + s;
                const float f = fbuf[buf][s*NTAGS + n];
                if (ph == 0) fv_sh[n] = fv;      // same-wave lockstep publish
                double bestv = -1e300; int bestp = 0;
                #pragma unroll
                for (int i=0;i<16;++i){
                    const int p = ph*16 + i;
                    const double v = fv_sh[p] + tr[i];
                    if (v > bestv){ bestv = v; bestp = p; }   // strict > = first index
                }
                const double ov = __shfl_xor(bestv, 32, 64);
                const int    op = __shfl_xor(bestp, 32, 64);
                const double lowv  = ph ? ov    : bestv;
                const int    lowp  = ph ? op    : bestp;
                const double highv = ph ? bestv : ov;
                const int    highp = ph ? bestp : op;
                double wvv = lowv; int wp = lowp;
                if (highv > lowv){ wvv = highv; wp = highp; } // low half wins ties
                if (ph == 0) bp_g[(size_t)t*NTAGS + n] = (unsigned char)wp;
                fv = wvv + (double)f;
            }
        } else if (cc + 1 < NCH){
            const int nb = (cc+1) & 1;
            const float* src = feats + (size_t)(cc+1)*CH*NTAGS;
            for (int idx = j - 64; idx < CH*NTAGS; idx += 192) fbuf[nb][idx] = src[idx];
        }
        __syncthreads();
    }

    if (scanlane && ph == 0) term_sh[n] = fv + (double)trans[STOP_TAG*NTAGS + n];
    __syncthreads();
    if (j == 0){
        double bv = term_sh[0]; int bi = 0;
        for (int p = 1; p < NTAGS; ++p){
            if (term_sh[p] > bv){ bv = term_sh[p]; bi = p; }
        }
        out[0] = (float)bv;
        out[1 + (T_LEN-1)] = (float)bi;
        best_sh = bi;
    }
    __threadfence();
    __syncthreads();
    // backtrace, 1024-step LDS chunks
    unsigned char* bp_sh = reinterpret_cast<unsigned char*>(fbuf);
    int b = best_sh;
    for (int cc2 = 3; cc2 >= 0; --cc2){
        const u32* src = reinterpret_cast<const u32*>(bp_g + (size_t)cc2*1024*NTAGS);
        u32* dst = reinterpret_cast<u32*>(bp_sh);
        for (int idx = j; idx < 8192; idx += 256) dst[idx] = src[idx];
        __syncthreads();
        if (j == 0){
            for (int tt = 1023; tt >= 0; --tt){
                const int t = cc2*1024 + tt;
                if (t == 0) break;                 // step into <START> dropped
                const int nb2 = bp_sh[tt*NTAGS + b];
                out[1 + (t-1)] = (float)nb2;
                b = nb2;
            }
        }
        __syncthreads();
    }
}

// ---------------------------------------------------------------------------
extern "C" void kernel_launch(void* const* d_in, const int* in_sizes, int n_in,
                              void* d_out, int out_size, void* d_ws, size_t ws_size,
                              hipStream_t stream)
{
    const int*   seq   = (const int*)  d_in[0];
    const float* E     = (const float*)d_in[1];
    const float* Wih_f = (const float*)d_in[2];
    const float* Whh_f = (const float*)d_in[3];
    const float* bih_f = (const float*)d_in[4];
    const float* bhh_f = (const float*)d_in[5];
    const float* Wih_b = (const float*)d_in[6];
    const float* Whh_b = (const float*)d_in[7];
    const float* bih_b = (const float*)d_in[8];
    const float* bhh_b = (const float*)d_in[9];
    const float* h0    = (const float*)d_in[10];
    const float* c0    = (const float*)d_in[11];
    const float* W_out = (const float*)d_in[12];
    const float* b_out = (const float*)d_in[13];
    const float* trans = (const float*)d_in[14];

    char* ws = (char*)d_ws;
    float* xg_f  = (float*)(ws);                                 // 16 MB
    float* xg_b  = (float*)(ws + (size_t)(16u<<20));             // 16 MB
    float* hs_f  = (float*)(ws + (size_t)(32u<<20));             // 4 MB
    float* hs_b  = (float*)(ws + (size_t)(36u<<20));             // 4 MB
    float* feats = (float*)(ws + (size_t)(40u<<20));             // 512 KB
    unsigned char* bp = (unsigned char*)(ws + (size_t)(40u<<20) + (512u<<10)); // 128 KB
    u64* hbuf    = (u64*)(ws + (size_t)(40u<<20) + (640u<<10));  // 8 KB

    k_xg<<<dim3(4096), dim3(256), 0, stream>>>(seq, E, Wih_f, bih_f, bhh_f,
                                               Wih_b, bih_b, bhh_b, xg_f, xg_b);
    k_lstm<<<dim3(8), dim3(256), 0, stream>>>(Whh_f, Whh_b, xg_f, xg_b, h0, c0, hs_f, hs_b, hbuf);
    k_feats<<<dim3(512), dim3(256), 0, stream>>>(hs_f, hs_b, W_out, b_out, feats);
    k_viterbi<<<dim3(1), dim3(256), 0, stream>>>(feats, trans, bp, (float*)d_out);
}